// Round 3
// baseline (168.795 us; speedup 1.0000x reference)
//
#include <hip/hip_runtime.h>

// KANN_4578435137547: quadratic Lagrange FEM basis + weight contraction.
// Single-pass, one block per (sample, array): x/nl/basis are wave-uniform,
// zero path is ~fill-kernel cheap. Outputs (flat f32):
//   t[32768], dt[32768], ddt[32768], phi/dphi/ddphi each [32768][2049].

#define KN_NODES    2049
#define KN_SAMPLES  4096
#define KN_IK       (KN_SAMPLES * 8)                   // 32768
#define KN_HEAD     (3 * KN_IK)                        // 98304
#define KN_PHI_LEN  ((size_t)KN_IK * KN_NODES)         // 67,141,632
#define KN_ROWF     (8 * KN_NODES)                     // 16392 floats per block
#define KN_NF4      (KN_ROWF / 4)                      // 4098 float4 per block

__global__ __launch_bounds__(256)
void KANN_all(const float* __restrict__ x, const float* __restrict__ w,
              float* __restrict__ out) {
    const int i = blockIdx.x;     // sample
    const int y = blockIdx.y;     // 0=phi, 1=dphi, 2=ddphi

    // Wave-uniform per block: coordinate + basis values.
    float xv  = x[i];
    float xs  = 2048.0f * xv;
    float fid = floorf(0.5f * xs);
    fid = fminf(fmaxf(fid, 0.0f), 1023.0f);
    int   nl  = 2 * (int)fid;                 // even, [0, 2046]
    float x_t = xs - (float)nl - 1.0f;        // [-1, 1]

    float b0, b1, b2;
    if (y == 0)      { b0 = 0.5f * x_t * (x_t - 1.0f); b1 = 1.0f - x_t * x_t; b2 = 0.5f * x_t * (x_t + 1.0f); }
    else if (y == 1) { b0 = (x_t - 0.5f) * 2048.0f; b1 = -4096.0f * x_t; b2 = (x_t + 0.5f) * 2048.0f; }
    else             { b0 = 4194304.0f; b1 = -8388608.0f; b2 = 4194304.0f; }

    // Head contractions folded into y==0 blocks, lanes 0..7 (k index).
    if (y == 0 && threadIdx.x < 8) {
        int k = threadIdx.x;
        const float* wk = w + k * KN_NODES + nl;
        float w0 = wk[0], w1 = wk[1], w2 = wk[2];
        float p0 = 0.5f * x_t * (x_t - 1.0f);
        float p1 = 1.0f - x_t * x_t;
        float p2 = 0.5f * x_t * (x_t + 1.0f);
        int ik = i * 8 + k;
        out[ik]             = w0 * p0 + w1 * p1 + w2 * p2;
        out[KN_IK + ik]     = (w0 * (x_t - 0.5f) - 2.0f * w1 * x_t + w2 * (x_t + 0.5f)) * 2048.0f;
        out[2 * KN_IK + ik] = (w0 - 2.0f * w1 + w2) * 4194304.0f;
    }

    // Dense region: rows 8i..8i+7 of array y, 4098 float4s, 16B-aligned base.
    float* base = out + KN_HEAD + (size_t)y * KN_PHI_LEN + (size_t)i * KN_ROWF;
    const float4 zero4 = make_float4(0.0f, 0.0f, 0.0f, 0.0f);

    for (int f = threadIdx.x; f < KN_NF4; f += 256) {
        int e0 = f << 2;
        int r  = e0 >> 11;                    // 2049 = 2^11 + 1
        int c  = (e0 & 2047) - r;
        if (c < 0) { r -= 1; c += KN_NODES; } // c = col of first element, [0,2048]
        int  d0   = c - nl;
        bool hot  = (d0 >= -3 && d0 <= 2) || (c >= 2046 && nl <= 2);
        if (__builtin_expect(__any(hot), 0)) {
            float vv[4];
#pragma unroll
            for (int j = 0; j < 4; ++j) {
                int cj = c + j;
                if (cj > 2048) cj -= KN_NODES;   // wraps into next row (same nl)
                int d = cj - nl;
                vv[j] = (d == 0) ? b0 : ((d == 1) ? b1 : ((d == 2) ? b2 : 0.0f));
            }
            *reinterpret_cast<float4*>(base + e0) = make_float4(vv[0], vv[1], vv[2], vv[3]);
        } else {
            *reinterpret_cast<float4*>(base + e0) = zero4;
        }
    }
}

extern "C" void kernel_launch(void* const* d_in, const int* in_sizes, int n_in,
                              void* d_out, int out_size, void* d_ws, size_t ws_size,
                              hipStream_t stream) {
    const float* x = (const float*)d_in[0];
    const float* w = (const float*)d_in[1];
    float* out = (float*)d_out;
    KANN_all<<<dim3(KN_SAMPLES, 3), dim3(256), 0, stream>>>(x, w, out);
}